// Round 1
// baseline (2314.493 us; speedup 1.0000x reference)
//
#include <hip/hip_runtime.h>
#include <hip/hip_bf16.h>

#define B_  4
#define C_  256
#define CB_ 32
#define N_  4096

// ---------------------------------------------------------------------------
// Workspace layout (12 MiB + 128 KiB total):
//   q     fp32 [B][CB][N]   @ 0        (2 MiB)
//   k     fp32 [B][CB][N]   @ 2 MiB    (2 MiB)
//   v     bf16 [B][C ][N]   @ 4 MiB    (8 MiB)
//   rowM  fp32 [B][N]       @ 12 MiB   (64 KiB)   max_n q_m.k_n
//   rowZi fp32 [B][N]       @ 12M+64K  (64 KiB)   1 / sum_n exp(s - M)
// ---------------------------------------------------------------------------

// Fused QKV projection: one 320x256 GEMM against x[b,:,n].
// blockIdx.y (yt): 0..3 -> Wv rows yt*64..; 4 -> rows 0..31 = Wq, 32..63 = Wk.
__global__ __launch_bounds__(256) void qkv_gemm(
    const float* __restrict__ x,
    const float* __restrict__ Wq, const float* __restrict__ bq,
    const float* __restrict__ Wk, const float* __restrict__ bk,
    const float* __restrict__ Wv, const float* __restrict__ bv,
    float* __restrict__ q, float* __restrict__ k, __hip_bfloat16* __restrict__ v)
{
    const int b = blockIdx.z, yt = blockIdx.y, n0 = blockIdx.x * 64;
    const int tid = threadIdx.x, tx = tid & 15, ty = tid >> 4;
    __shared__ float sX[16][64];
    __shared__ float sW[64][17];
    const float* xb = x + (size_t)b * C_ * N_;
    float acc[4][4] = {};
    for (int kc = 0; kc < C_; kc += 16) {
#pragma unroll
        for (int i = 0; i < 4; ++i) {
            int e = tid + 256 * i, r = e >> 6, cn = e & 63;
            sX[r][cn] = xb[(size_t)(kc + r) * N_ + n0 + cn];
        }
#pragma unroll
        for (int i = 0; i < 4; ++i) {
            int e = tid + 256 * i, co = e >> 4, cc = e & 15;
            int cg = kc + cc;
            float w;
            if (yt < 4)       w = Wv[(yt * 64 + co) * C_ + cg];
            else if (co < 32) w = Wq[co * C_ + cg];
            else              w = Wk[(co - 32) * C_ + cg];
            sW[co][cc] = w;
        }
        __syncthreads();
#pragma unroll
        for (int cc = 0; cc < 16; ++cc) {
            float a[4], bb[4];
#pragma unroll
            for (int i = 0; i < 4; ++i) a[i] = sW[ty * 4 + i][cc];
#pragma unroll
            for (int j = 0; j < 4; ++j) bb[j] = sX[cc][tx * 4 + j];
#pragma unroll
            for (int i = 0; i < 4; ++i)
#pragma unroll
                for (int j = 0; j < 4; ++j) acc[i][j] = fmaf(a[i], bb[j], acc[i][j]);
        }
        __syncthreads();
    }
#pragma unroll
    for (int i = 0; i < 4; ++i) {
        int co = ty * 4 + i;
        float bias;
        if (yt < 4)       bias = bv[yt * 64 + co];
        else if (co < 32) bias = bq[co];
        else              bias = bk[co - 32];
#pragma unroll
        for (int j = 0; j < 4; ++j) {
            int n = n0 + tx * 4 + j;
            float r = acc[i][j] + bias;
            if (yt < 4)
                v[((size_t)b * C_ + yt * 64 + co) * N_ + n] = __float2bfloat16(r);
            else if (co < 32)
                q[((size_t)b * CB_ + co) * N_ + n] = r;
            else
                k[((size_t)b * CB_ + (co - 32)) * N_ + n] = r;
        }
    }
}

// Row stats over n for each m: M(m) = max_n q_m.k_n ; Zi(m) = 1/sum_n exp(s-M).
// Block: 64 m (lane) x 4 n-splits (wave). k loads are wave-uniform (broadcast).
__global__ __launch_bounds__(256) void row_stats(
    const float* __restrict__ q, const float* __restrict__ k,
    float* __restrict__ rowM, float* __restrict__ rowZi)
{
    const int b = blockIdx.y, m0 = blockIdx.x * 64;
    const int tid = threadIdx.x, mi = tid & 63, ns = tid >> 6;
    const float* qb = q + (size_t)b * CB_ * N_;
    const float* kb = k + (size_t)b * CB_ * N_;
    float qr[CB_];
#pragma unroll
    for (int d = 0; d < CB_; ++d) qr[d] = qb[(size_t)d * N_ + m0 + mi];
    float mrun = -1e30f, zrun = 0.f;
    const int nbeg = ns * 1024;
    for (int n = nbeg; n < nbeg + 1024; n += 4) {
        float s0 = 0.f, s1 = 0.f, s2 = 0.f, s3 = 0.f;
#pragma unroll
        for (int d = 0; d < CB_; ++d) {
            float4 kv = *reinterpret_cast<const float4*>(&kb[(size_t)d * N_ + n]);
            s0 = fmaf(qr[d], kv.x, s0); s1 = fmaf(qr[d], kv.y, s1);
            s2 = fmaf(qr[d], kv.z, s2); s3 = fmaf(qr[d], kv.w, s3);
        }
        float tmax = fmaxf(fmaxf(s0, s1), fmaxf(s2, s3));
        if (tmax > mrun) { zrun *= __expf(mrun - tmax); mrun = tmax; }
        zrun += __expf(s0 - mrun) + __expf(s1 - mrun) +
                __expf(s2 - mrun) + __expf(s3 - mrun);
    }
    __shared__ float sM[4][64], sZ[4][64];
    sM[ns][mi] = mrun; sZ[ns][mi] = zrun;
    __syncthreads();
    if (tid < 64) {
        float M = sM[0][mi];
#pragma unroll
        for (int i = 1; i < 4; ++i) M = fmaxf(M, sM[i][mi]);
        float Z = 0.f;
#pragma unroll
        for (int i = 0; i < 4; ++i) Z += sZ[i][mi] * __expf(sM[i][mi] - M);
        rowM [(size_t)b * N_ + m0 + mi] = M;
        rowZi[(size_t)b * N_ + m0 + mi] = 1.0f / Z;
    }
}

// out[c,n] = x[c,n] + sum_m v[c,m] * exp(q_m.k_n - M(m)) * Zi(m)
// Block tile: 64c x 64n; m-loop in steps of 32 with LDS-staged Q, V, P.
__global__ __launch_bounds__(256) void pv_attn(
    const float* __restrict__ q, const float* __restrict__ k,
    const __hip_bfloat16* __restrict__ v,
    const float* __restrict__ rowM, const float* __restrict__ rowZi,
    const float* __restrict__ x, float* __restrict__ out)
{
    const int b = blockIdx.z, c0 = blockIdx.y * 64, n0 = blockIdx.x * 64;
    const int tid = threadIdx.x, tx = tid & 15, ty = tid >> 4;
    __shared__ float sK[CB_][64];
    __shared__ float sQ[CB_][32];
    __shared__ float sP[32][64];
    __shared__ float sV[64][33];
    const float* qb = q + (size_t)b * CB_ * N_;
    const float* kb = k + (size_t)b * CB_ * N_;
    const __hip_bfloat16* vb = v + (size_t)b * C_ * N_;
    const float* Mb = rowM  + (size_t)b * N_;
    const float* Zb = rowZi + (size_t)b * N_;

#pragma unroll
    for (int i = 0; i < 8; ++i) {           // stage K tile once (reused all m0)
        int e = tid + 256 * i, d = e >> 6, nn = e & 63;
        sK[d][nn] = kb[(size_t)d * N_ + n0 + nn];
    }
    float acc[4][4] = {};
    for (int m0 = 0; m0 < N_; m0 += 32) {
        __syncthreads();                    // prior accumulate done (also fences sK once)
#pragma unroll
        for (int i = 0; i < 4; ++i) {       // stage Q tile 32d x 32m
            int e = tid + 256 * i, d = e >> 5, mm = e & 31;
            sQ[d][mm] = qb[(size_t)d * N_ + m0 + mm];
        }
#pragma unroll
        for (int i = 0; i < 8; ++i) {       // stage V tile 64c x 32m
            int e = tid + 256 * i, cc = e >> 5, mm = e & 31;
            sV[cc][mm] = __bfloat162float(vb[(size_t)(c0 + cc) * N_ + m0 + mm]);
        }
        __syncthreads();
#pragma unroll
        for (int i = 0; i < 8; ++i) {       // P tile 32m x 64n
            int e = tid + 256 * i, mm = e >> 6, nn = e & 63;
            float s = 0.f;
#pragma unroll
            for (int d = 0; d < CB_; ++d) s = fmaf(sQ[d][mm], sK[d][nn], s);
            sP[mm][nn] = __expf(s - Mb[m0 + mm]) * Zb[m0 + mm];
        }
        __syncthreads();
#pragma unroll
        for (int mm = 0; mm < 32; ++mm) {   // acc += V[:,mm] outer P[mm,:]
            float vv[4], pp[4];
#pragma unroll
            for (int i = 0; i < 4; ++i) vv[i] = sV[ty * 4 + i][mm];
#pragma unroll
            for (int j = 0; j < 4; ++j) pp[j] = sP[mm][tx * 4 + j];
#pragma unroll
            for (int i = 0; i < 4; ++i)
#pragma unroll
                for (int j = 0; j < 4; ++j) acc[i][j] = fmaf(vv[i], pp[j], acc[i][j]);
        }
    }
#pragma unroll
    for (int i = 0; i < 4; ++i) {
        int c = c0 + ty * 4 + i;
#pragma unroll
        for (int j = 0; j < 4; ++j) {
            int n = n0 + tx * 4 + j;
            size_t idx = ((size_t)b * C_ + c) * N_ + n;
            out[idx] = acc[i][j] + x[idx];
        }
    }
}

extern "C" void kernel_launch(void* const* d_in, const int* in_sizes, int n_in,
                              void* d_out, int out_size, void* d_ws, size_t ws_size,
                              hipStream_t stream)
{
    const float* x  = (const float*)d_in[0];
    const float* Wq = (const float*)d_in[1];
    const float* bq = (const float*)d_in[2];
    const float* Wk = (const float*)d_in[3];
    const float* bk = (const float*)d_in[4];
    const float* Wv = (const float*)d_in[5];
    const float* bv = (const float*)d_in[6];
    float* out = (float*)d_out;

    char* ws = (char*)d_ws;
    float*           qw    = (float*)(ws);
    float*           kw    = (float*)(ws + (2u << 20));
    __hip_bfloat16*  vw    = (__hip_bfloat16*)(ws + (4u << 20));
    float*           rowM  = (float*)(ws + (12u << 20));
    float*           rowZi = (float*)(ws + (12u << 20) + (64u << 10));

    qkv_gemm<<<dim3(N_ / 64, 5, B_), 256, 0, stream>>>(x, Wq, bq, Wk, bk, Wv, bv,
                                                       qw, kw, vw);
    row_stats<<<dim3(N_ / 64, B_), 256, 0, stream>>>(qw, kw, rowM, rowZi);
    pv_attn<<<dim3(N_ / 64, C_ / 64, B_), 256, 0, stream>>>(qw, kw, vw, rowM, rowZi,
                                                            x, out);
}

// Round 2
// 180.330 us; speedup vs baseline: 12.8348x; 12.8348x over previous
//
#include <hip/hip_runtime.h>
#include <hip/hip_bf16.h>

#define B_  4
#define C_  256
#define CB_ 32
#define N_  4096

typedef short bf16x8 __attribute__((ext_vector_type(8)));
typedef float f32x4  __attribute__((ext_vector_type(4)));

static __device__ __forceinline__ bf16x8 ld_bf8(const __hip_bfloat16* p) {
    return *reinterpret_cast<const bf16x8*>(p);
}

// ---------------------------------------------------------------------------
// Workspace layout:
//   Wc    bf16 [320][256]   @ 0        (160 KiB)  rows 0..31=Wq, 32..63=Wk, 64..319=Wv
//   qt    bf16 [B][N][32]   @ 256 KiB  (1 MiB)    q transposed
//   kt    bf16 [B][N][32]   @ 1.25 MiB (1 MiB)    k transposed
//   rowM  fp32 [B][N]       @ 2.25 MiB (64 KiB)
//   rowZi fp32 [B][N]       @ 2.25M+64K(64 KiB)
//   v     bf16 [B][C][N]    @ 4 MiB    (8 MiB)
// ---------------------------------------------------------------------------

// Convert the three weight matrices into one 320x256 bf16 matrix.
__global__ __launch_bounds__(256) void wconv(
    const float* __restrict__ Wq, const float* __restrict__ Wk,
    const float* __restrict__ Wv, __hip_bfloat16* __restrict__ Wc)
{
    int idx = (blockIdx.x * 256 + threadIdx.x) * 4;
    if (idx >= 320 * 256) return;
    int o = idx >> 8, c = idx & 255;
    const float* src = o < 32 ? Wq + o * 256 + c
                     : o < 64 ? Wk + (o - 32) * 256 + c
                              : Wv + (o - 64) * 256 + c;
    float4 f = *reinterpret_cast<const float4*>(src);
    union { __hip_bfloat16 h[4]; uint2 u; } pk;
    pk.h[0] = __float2bfloat16(f.x); pk.h[1] = __float2bfloat16(f.y);
    pk.h[2] = __float2bfloat16(f.z); pk.h[3] = __float2bfloat16(f.w);
    *reinterpret_cast<uint2*>(Wc + idx) = pk.u;
}

// Fused QKV projection, MFMA. Block: 64 n, all 320 output rows, 4 waves.
// Wave w owns o-frags {w, w+4, ..., w+16}.
__global__ __launch_bounds__(256) void qkv_gemm(
    const float* __restrict__ x, const __hip_bfloat16* __restrict__ Wc,
    const float* __restrict__ bq, const float* __restrict__ bk,
    const float* __restrict__ bv,
    __hip_bfloat16* __restrict__ qt, __hip_bfloat16* __restrict__ kt,
    __hip_bfloat16* __restrict__ v)
{
    const int b = blockIdx.y, n0 = blockIdx.x * 64;
    const int tid = threadIdx.x, lane = tid & 63, w = tid >> 6;
    const int lg = lane >> 4, lr = lane & 15;
    __shared__ __attribute__((aligned(16))) __hip_bfloat16 T[2][64][40]; // [n][c] per c-step
    const float* xb = x + (size_t)b * C_ * N_;

    f32x4 acc[5][4] = {};
    for (int s = 0; s < 8; ++s) {
        const int c0 = s * 32, buf = s & 1;
        // stage x[c0..c0+32)[n0..n0+64) as bf16 transposed
#pragma unroll
        for (int p = 0; p < 2; ++p) {
            int f4 = tid + 256 * p, cl = f4 >> 4, n4 = (f4 & 15) * 4;
            float4 f = *reinterpret_cast<const float4*>(
                &xb[(size_t)(c0 + cl) * N_ + n0 + n4]);
            T[buf][n4 + 0][cl] = __float2bfloat16(f.x);
            T[buf][n4 + 1][cl] = __float2bfloat16(f.y);
            T[buf][n4 + 2][cl] = __float2bfloat16(f.z);
            T[buf][n4 + 3][cl] = __float2bfloat16(f.w);
        }
        __syncthreads();
        bf16x8 bf[4];
#pragma unroll
        for (int nf = 0; nf < 4; ++nf)
            bf[nf] = *reinterpret_cast<const bf16x8*>(&T[buf][nf * 16 + lr][lg * 8]);
#pragma unroll
        for (int t = 0; t < 5; ++t) {
            const int of = w + 4 * t;
            bf16x8 af = ld_bf8(Wc + (size_t)(of * 16 + lr) * 256 + c0 + lg * 8);
#pragma unroll
            for (int nf = 0; nf < 4; ++nf)
                acc[t][nf] = __builtin_amdgcn_mfma_f32_16x16x32_bf16(af, bf[nf], acc[t][nf], 0, 0, 0);
        }
    }
#pragma unroll
    for (int t = 0; t < 5; ++t) {
        const int of = w + 4 * t, ob = of * 16 + lg * 4;
        float bias[4];
#pragma unroll
        for (int i = 0; i < 4; ++i) {
            int o = ob + i;
            bias[i] = o < 32 ? bq[o] : o < 64 ? bk[o - 32] : bv[o - 64];
        }
#pragma unroll
        for (int nf = 0; nf < 4; ++nf) {
            const int n = n0 + nf * 16 + lr;
            if (ob < 64) {
                union { __hip_bfloat16 h[4]; uint2 u; } pk;
#pragma unroll
                for (int i = 0; i < 4; ++i)
                    pk.h[i] = __float2bfloat16(acc[t][nf][i] + bias[i]);
                __hip_bfloat16* dst = ob < 32
                    ? qt + ((size_t)b * N_ + n) * CB_ + ob
                    : kt + ((size_t)b * N_ + n) * CB_ + (ob - 32);
                *reinterpret_cast<uint2*>(dst) = pk.u;
            } else {
#pragma unroll
                for (int i = 0; i < 4; ++i)
                    v[((size_t)b * C_ + (ob - 64 + i)) * N_ + n] =
                        __float2bfloat16(acc[t][nf][i] + bias[i]);
            }
        }
    }
}

// Row stats via MFMA: M(m)=max_n S, Zi(m)=1/sum_n exp(S-M). Wave w: 16 m-rows.
__global__ __launch_bounds__(256) void row_stats(
    const __hip_bfloat16* __restrict__ qt, const __hip_bfloat16* __restrict__ kt,
    float* __restrict__ rowM, float* __restrict__ rowZi)
{
    const int b = blockIdx.y, m0 = blockIdx.x * 64;
    const int tid = threadIdx.x, lane = tid & 63, w = tid >> 6;
    const int lg = lane >> 4, lr = lane & 15;
    const __hip_bfloat16* qtb = qt + (size_t)b * N_ * CB_;
    const __hip_bfloat16* ktb = kt + (size_t)b * N_ * CB_;
    const int mrow = m0 + w * 16;
    bf16x8 qf = ld_bf8(qtb + (size_t)(mrow + lr) * CB_ + lg * 8);
    float rm[4] = {-1e30f, -1e30f, -1e30f, -1e30f};
    float rz[4] = {0.f, 0.f, 0.f, 0.f};
    const f32x4 zero = {0.f, 0.f, 0.f, 0.f};
    for (int n = 0; n < N_; n += 64) {
        f32x4 sf[4];
#pragma unroll
        for (int nf = 0; nf < 4; ++nf) {
            bf16x8 kf = ld_bf8(ktb + (size_t)(n + nf * 16 + lr) * CB_ + lg * 8);
            sf[nf] = __builtin_amdgcn_mfma_f32_16x16x32_bf16(qf, kf, zero, 0, 0, 0);
        }
#pragma unroll
        for (int i = 0; i < 4; ++i) {
            float tm = fmaxf(fmaxf(sf[0][i], sf[1][i]), fmaxf(sf[2][i], sf[3][i]));
            if (tm > rm[i]) { rz[i] *= __expf(rm[i] - tm); rm[i] = tm; }
            rz[i] += __expf(sf[0][i] - rm[i]) + __expf(sf[1][i] - rm[i]) +
                     __expf(sf[2][i] - rm[i]) + __expf(sf[3][i] - rm[i]);
        }
    }
#pragma unroll
    for (int off = 1; off < 16; off <<= 1) {
#pragma unroll
        for (int i = 0; i < 4; ++i) {
            float om = __shfl_xor(rm[i], off);
            float oz = __shfl_xor(rz[i], off);
            float nm = fmaxf(rm[i], om);
            rz[i] = rz[i] * __expf(rm[i] - nm) + oz * __expf(om - nm);
            rm[i] = nm;
        }
    }
    if (lr == 0) {
#pragma unroll
        for (int i = 0; i < 4; ++i) {
            rowM [(size_t)b * N_ + mrow + lg * 4 + i] = rm[i];
            rowZi[(size_t)b * N_ + mrow + lg * 4 + i] = 1.0f / rz[i];
        }
    }
}

// out[c,n] = x[c,n] + sum_m v[c,m] * exp(S(m,n)-M(m))*Zi(m), S recomputed by MFMA.
// Block: 128 c x 64 n, 4 waves (wave w: 32 c). m-steps of 64.
#define PST 72
__global__ __launch_bounds__(256) void pv_attn(
    const __hip_bfloat16* __restrict__ qt, const __hip_bfloat16* __restrict__ kt,
    const __hip_bfloat16* __restrict__ v,
    const float* __restrict__ rowM, const float* __restrict__ rowZi,
    const float* __restrict__ x, float* __restrict__ out)
{
    const int b = blockIdx.z, c0 = blockIdx.y * 128, n0 = blockIdx.x * 64;
    const int tid = threadIdx.x, lane = tid & 63, w = tid >> 6;
    const int lg = lane >> 4, lr = lane & 15;
    __shared__ __attribute__((aligned(16))) __hip_bfloat16 Pt[2][64][PST]; // [n][m]
    const __hip_bfloat16* qtb = qt + (size_t)b * N_ * CB_;
    const __hip_bfloat16* ktb = kt + (size_t)b * N_ * CB_;
    const __hip_bfloat16* vb  = v  + (size_t)b * C_ * N_;
    const float* Mb = rowM  + (size_t)b * N_;
    const float* Zb = rowZi + (size_t)b * N_;
    const f32x4 zero = {0.f, 0.f, 0.f, 0.f};

    bf16x8 kf[4];
#pragma unroll
    for (int nf = 0; nf < 4; ++nf)
        kf[nf] = ld_bf8(ktb + (size_t)(n0 + nf * 16 + lr) * CB_ + lg * 8);

    f32x4 acc[2][4] = {};
    for (int m0 = 0; m0 < N_; m0 += 64) {
        const int buf = (m0 >> 6) & 1;
        const int mrow = m0 + w * 16;
        // S for 16 m-rows x 64 n, then P -> LDS (transposed [n][m])
        bf16x8 qf = ld_bf8(qtb + (size_t)(mrow + lr) * CB_ + lg * 8);
        float4 Mv = *reinterpret_cast<const float4*>(Mb + mrow + lg * 4);
        float4 Zv = *reinterpret_cast<const float4*>(Zb + mrow + lg * 4);
        float mv[4] = {Mv.x, Mv.y, Mv.z, Mv.w};
        float zv[4] = {Zv.x, Zv.y, Zv.z, Zv.w};
#pragma unroll
        for (int nf = 0; nf < 4; ++nf) {
            f32x4 sf = __builtin_amdgcn_mfma_f32_16x16x32_bf16(qf, kf[nf], zero, 0, 0, 0);
            union { __hip_bfloat16 h[4]; uint2 u; } pk;
#pragma unroll
            for (int i = 0; i < 4; ++i)
                pk.h[i] = __float2bfloat16(__expf(sf[i] - mv[i]) * zv[i]);
            *reinterpret_cast<uint2*>(&Pt[buf][nf * 16 + lr][w * 16 + lg * 4]) = pk.u;
        }
        __syncthreads();
        // PV: acc[c-frag][n-frag] += V[c, m-tile] * P[m-tile, n]
#pragma unroll
        for (int kc = 0; kc < 2; ++kc) {
            bf16x8 pb[4];
#pragma unroll
            for (int nf = 0; nf < 4; ++nf)
                pb[nf] = *reinterpret_cast<const bf16x8*>(&Pt[buf][nf * 16 + lr][kc * 32 + lg * 8]);
#pragma unroll
            for (int cf = 0; cf < 2; ++cf) {
                bf16x8 va = ld_bf8(vb + (size_t)(c0 + w * 32 + cf * 16 + lr) * N_
                                      + m0 + kc * 32 + lg * 8);
#pragma unroll
                for (int nf = 0; nf < 4; ++nf)
                    acc[cf][nf] = __builtin_amdgcn_mfma_f32_16x16x32_bf16(va, pb[nf], acc[cf][nf], 0, 0, 0);
            }
        }
    }
#pragma unroll
    for (int cf = 0; cf < 2; ++cf) {
#pragma unroll
        for (int nf = 0; nf < 4; ++nf) {
            const int n = n0 + nf * 16 + lr;
#pragma unroll
            for (int i = 0; i < 4; ++i) {
                const int c = c0 + w * 32 + cf * 16 + lg * 4 + i;
                const size_t idx = ((size_t)b * C_ + c) * N_ + n;
                out[idx] = acc[cf][nf][i] + x[idx];
            }
        }
    }
}

extern "C" void kernel_launch(void* const* d_in, const int* in_sizes, int n_in,
                              void* d_out, int out_size, void* d_ws, size_t ws_size,
                              hipStream_t stream)
{
    const float* x  = (const float*)d_in[0];
    const float* Wq = (const float*)d_in[1];
    const float* bq = (const float*)d_in[2];
    const float* Wk = (const float*)d_in[3];
    const float* bk = (const float*)d_in[4];
    const float* Wv = (const float*)d_in[5];
    const float* bv = (const float*)d_in[6];
    float* out = (float*)d_out;

    char* ws = (char*)d_ws;
    __hip_bfloat16* Wc    = (__hip_bfloat16*)(ws);
    __hip_bfloat16* qt    = (__hip_bfloat16*)(ws + (256u << 10));
    __hip_bfloat16* kt    = (__hip_bfloat16*)(ws + (256u << 10) + (1u << 20));
    float*          rowM  = (float*)(ws + (256u << 10) + (2u << 20));
    float*          rowZi = (float*)(ws + (256u << 10) + (2u << 20) + (64u << 10));
    __hip_bfloat16* vw    = (__hip_bfloat16*)(ws + (4u << 20));

    wconv<<<80, 256, 0, stream>>>(Wq, Wk, Wv, Wc);
    qkv_gemm<<<dim3(N_ / 64, B_), 256, 0, stream>>>(x, Wc, bq, bk, bv, qt, kt, vw);
    row_stats<<<dim3(N_ / 64, B_), 256, 0, stream>>>(qt, kt, rowM, rowZi);
    pv_attn<<<dim3(N_ / 64, 2, B_), 256, 0, stream>>>(qt, kt, vw, rowM, rowZi, x, out);
}